// Round 5
// baseline (470.875 us; speedup 1.0000x reference)
//
#include <hip/hip_runtime.h>
#include <hip/hip_bf16.h>

// Sizes (hard-coded from reference): B=32, T=512, D=64, H=64, S=4096, 4H=256, 2H=128
#define T_ 512

typedef __attribute__((ext_vector_type(8))) short short8;
typedef __attribute__((ext_vector_type(4))) float f32x4;

__device__ __forceinline__ float fast_rcp(float x){ return __builtin_amdgcn_rcpf(x); }
// Clamp-free: exp->inf saturates cleanly through rcp (sigmoid->0/1, tanh->+-1)
__device__ __forceinline__ float sigmoid_f(float x){
  return fast_rcp(1.f + __expf(-x));
}
__device__ __forceinline__ float tanh_f(float x){
  return fmaf(2.f, fast_rcp(1.f + __expf(-2.f*x)), -1.f);
}
__device__ __forceinline__ float gelu_f(float x){
  float u = 0.7978845608028654f*(x + 0.044715f*x*x*x);
  return 0.5f*x*(1.f + tanh_f(u));
}

// ---------------- Kernel 1: xg = enc @ Wx + bh (bias folded) ----------------
// enc [16384,64], Wx [64,256] -> xg [16384,256] fp32
__global__ __launch_bounds__(256, 1) void k_xg(const float* __restrict__ enc,
                                               const float* __restrict__ Wx,
                                               const float* __restrict__ bh,
                                               float* __restrict__ xg)
{
  __shared__ __align__(16) float es[64*64];
  int j = threadIdx.x;
  int g = blockIdx.x;                     // 256 blocks, 64 rows each
  const float* encg = enc + (size_t)g*64*64;
  for (int idx = j; idx < 64*64; idx += 256) es[idx] = encg[idx];
  float wx[64];
#pragma unroll
  for (int k = 0; k < 64; ++k) wx[k] = Wx[k*256 + j];   // column j in regs
  float bj = bh[j];
  __syncthreads();
  float* xo = xg + (size_t)g*64*256;
  for (int r = 0; r < 64; ++r){
    const float4* e4 = (const float4*)(es + r*64);
    float z0 = bj, z1 = 0.f, z2 = 0.f, z3 = 0.f;
#pragma unroll
    for (int k4 = 0; k4 < 16; ++k4){
      float4 v = e4[k4];
      z0 = fmaf(v.x, wx[4*k4+0], z0);
      z1 = fmaf(v.y, wx[4*k4+1], z1);
      z2 = fmaf(v.z, wx[4*k4+2], z2);
      z3 = fmaf(v.w, wx[4*k4+3], z3);
    }
    xo[r*256 + j] = (z0+z1)+(z2+z3);
  }
}

// ---------------- Kernel 2: persistent LSTM, one WG per batch ----------------
// Round-3 exchange structure + resident weights:
//  - wave w owns units [16w,16w+16): lane l computes gate g=(l>>4) of unit
//    m=16w+(l&15), i.e. column j=g*64+m of z. Wh[:,j] lives in 64 VGPRs
//    (launch_bounds(,1) lifts the 64-VGPR occupancy cap that silently forced
//    L2 reloads in rounds 2-3).
//  - h broadcast via double-buffered LDS float4 reads (LDS pipe overlaps the
//    64 VGPR-operand FMAs; no readlane SGPR hazards like round 4).
//  - z gate exchange intra-wave via 3x shfl_xor -> no LDS round trip for z.
//  - exactly ONE barrier per step; xg prefetched 4 steps deep.
__global__ __launch_bounds__(256, 1) void k_lstm(const float* __restrict__ xg,
                                                 const float* __restrict__ Wh,
                                                 float* __restrict__ hs)
{
  __shared__ __align__(16) float hb[2][64];
  int tid = threadIdx.x;
  int w = tid >> 6, l = tid & 63;
  int m = w*16 + (l & 15);              // unit owned (update lanes l<16)
  int g = l >> 4;                       // gate index 0..3 (i,f,g,o)
  int j = g*64 + m;                     // column of Wh/xg this thread computes
  int b = blockIdx.x;
  float wh[64];
#pragma unroll
  for (int k = 0; k < 64; ++k) wh[k] = Wh[k*256 + j];   // Wh[:,j] resident
  bool upd = (l < 16);
  float c = 0.f;
  if (tid < 64) hb[0][tid] = 0.f;
  const float* xr = xg + (size_t)b*T_*256;
  float* ho = hs + (size_t)b*T_*64;
  float xn0 = xr[j];                    // 4-deep prefetch pipeline
  float xn1 = xr[256 + j];
  float xn2 = xr[512 + j];
  float xn3 = xr[768 + j];
  __syncthreads();

#define LSTM_STEP(tt, xn)                                                     \
  {                                                                           \
    const float4* h4 = (const float4*)hb[(tt) & 1];                           \
    float z0 = (xn), z1 = 0.f, z2 = 0.f, z3 = 0.f;                            \
    if ((tt) + 4 < T_) (xn) = xr[(size_t)((tt) + 4)*256 + j];                 \
    _Pragma("unroll")                                                         \
    for (int k4 = 0; k4 < 16; ++k4){                                          \
      float4 v = h4[k4];                /* broadcast read, conflict-free */   \
      z0 = fmaf(v.x, wh[4*k4+0], z0);                                         \
      z1 = fmaf(v.y, wh[4*k4+1], z1);                                         \
      z2 = fmaf(v.z, wh[4*k4+2], z2);                                         \
      z3 = fmaf(v.w, wh[4*k4+3], z3);                                         \
    }                                                                         \
    float z = (z0+z1)+(z2+z3);                                                \
    float zB = __shfl_xor(z, 16);       /* lane<16: f-gate */                 \
    float zC = __shfl_xor(z, 32);       /* lane<16: g-gate */                 \
    float zD = __shfl_xor(z, 48);       /* lane<16: o-gate */                 \
    if (upd){                                                                 \
      c = sigmoid_f(zB)*c + sigmoid_f(z)*tanh_f(zC);                          \
      float h = sigmoid_f(zD)*tanh_f(c);                                      \
      hb[((tt)+1) & 1][m] = h;                                                \
      ho[(size_t)(tt)*64 + m] = h;                                            \
    }                                                                         \
    __syncthreads();                    /* write buf ready; read buf retired */\
  }

  for (int t = 0; t < T_; t += 4){
    LSTM_STEP(t,   xn0);
    LSTM_STEP(t+1, xn1);
    LSTM_STEP(t+2, xn2);
    LSTM_STEP(t+3, xn3);
  }
#undef LSTM_STEP
}

// ---------------- Kernel 3: fused MLP (LN+gelu twice), writes h2 as bf16 ----
// hs [16384,64] -> h2g [16384,128] bf16
__global__ __launch_bounds__(256, 1) void k_mlp(const float* __restrict__ hs,
    const float* __restrict__ W1, const float* __restrict__ b1,
    const float* __restrict__ g1, const float* __restrict__ be1,
    const float* __restrict__ W2, const float* __restrict__ b2,
    const float* __restrict__ g2, const float* __restrict__ be2,
    __hip_bfloat16* __restrict__ h2g)
{
  __shared__ __align__(16) float xs[2][64];
  __shared__ __align__(16) float vs[2][128];
  __shared__ float red[2][2][2];
  int tid = threadIdx.x;
  int jj = tid & 127, rg = tid >> 7;    // output column, row-group (2 rows per pass)
  int lane = tid & 63;
  int whalf = (tid >> 6) & 1;           // which wave within the row-group
  float w1c[64], w2c[128];
#pragma unroll
  for (int k = 0; k < 64; ++k) w1c[k] = W1[k*128 + jj];
#pragma unroll
  for (int k = 0; k < 128; ++k) w2c[k] = W2[k*128 + jj];
  float b1j = b1[jj], g1j = g1[jj], be1j = be1[jj];
  float b2j = b2[jj], g2j = g2[jj], be2j = be2[jj];
  int base = blockIdx.x * 64;           // 256 blocks x 64 rows
  for (int p = 0; p < 32; ++p){
    int r = base + p*2 + rg;
    if (whalf == 0) xs[rg][lane] = hs[(size_t)r*64 + lane];
    __syncthreads();                                    // B1: xs ready
    float a0 = b1j, a1 = 0.f;
    const float4* x4 = (const float4*)xs[rg];
#pragma unroll
    for (int k4 = 0; k4 < 16; ++k4){
      float4 v = x4[k4];
      a0 = fmaf(v.x, w1c[4*k4+0], a0);
      a1 = fmaf(v.y, w1c[4*k4+1], a1);
      a0 = fmaf(v.z, w1c[4*k4+2], a0);
      a1 = fmaf(v.w, w1c[4*k4+3], a1);
    }
    float a = a0 + a1;
    float s1 = a, s2 = a*a;
#pragma unroll
    for (int off = 32; off > 0; off >>= 1){
      s1 += __shfl_xor(s1, off, 64);
      s2 += __shfl_xor(s2, off, 64);
    }
    if (lane == 0){ red[rg][whalf][0] = s1; red[rg][whalf][1] = s2; }
    __syncthreads();                                    // B2: red ready
    s1 = red[rg][0][0] + red[rg][1][0];
    s2 = red[rg][0][1] + red[rg][1][1];
    float mean = s1*(1.f/128.f);
    float var  = s2*(1.f/128.f) - mean*mean;
    float rstd = rsqrtf(var + 1e-6f);
    float y = gelu_f((a - mean)*rstd*g1j + be1j);
    vs[rg][jj] = y;
    __syncthreads();                                    // B3: vs ready (also orders red reuse)
    float c0 = b2j, c1 = 0.f;
    const float4* v4 = (const float4*)vs[rg];
#pragma unroll
    for (int k4 = 0; k4 < 32; ++k4){
      float4 v = v4[k4];
      c0 = fmaf(v.x, w2c[4*k4+0], c0);
      c1 = fmaf(v.y, w2c[4*k4+1], c1);
      c0 = fmaf(v.z, w2c[4*k4+2], c0);
      c1 = fmaf(v.w, w2c[4*k4+3], c1);
    }
    float cc = c0 + c1;
    float t1 = cc, t2 = cc*cc;
#pragma unroll
    for (int off = 32; off > 0; off >>= 1){
      t1 += __shfl_xor(t1, off, 64);
      t2 += __shfl_xor(t2, off, 64);
    }
    if (lane == 0){ red[rg][whalf][0] = t1; red[rg][whalf][1] = t2; }
    __syncthreads();                                    // B4: red2 ready
    t1 = red[rg][0][0] + red[rg][1][0];
    t2 = red[rg][0][1] + red[rg][1][1];
    mean = t1*(1.f/128.f);
    var  = t2*(1.f/128.f) - mean*mean;
    rstd = rsqrtf(var + 1e-6f);
    float z = gelu_f((cc - mean)*rstd*g2j + be2j);
    h2g[(size_t)r*128 + jj] = __float2bfloat16(z);
  }
}

// ---------------- Kernel 3.5: Wo fp32 [128,4096] -> WoT bf16 [4096,128] -----
__global__ __launch_bounds__(256, 1) void k_wot(const float* __restrict__ Wo,
                                                __hip_bfloat16* __restrict__ WoT)
{
  __shared__ __hip_bfloat16 tl[64][130];   // pad to dodge write conflicts
  int tid = threadIdx.x;
  int n0 = blockIdx.x * 64;                // 64 blocks of 64 n-columns
  for (int idx = tid; idx < 64*128; idx += 256){
    int k = idx >> 6, nl = idx & 63;       // coalesced read of Wo row k
    tl[nl][k] = __float2bfloat16(Wo[(size_t)k*4096 + n0 + nl]);
  }
  __syncthreads();
  for (int idx = tid; idx < 64*128; idx += 256){
    int nl = idx >> 7, k = idx & 127;      // coalesced write of WoT row
    WoT[(size_t)(n0 + nl)*128 + k] = tl[nl][k];
  }
}

// ---------------- Kernel 4: out = h2 @ Wo + bo via bf16 MFMA ----------------
// 128x128 block tile (4 waves 2x2, 4x4 fragments each).
// A=WoT (rows=n), B=h2g (rows=m) so D's reg axis runs along n -> float4 stores.
__global__ __launch_bounds__(256, 1) void k_out(const __hip_bfloat16* __restrict__ h2g,
                                                const __hip_bfloat16* __restrict__ WoT,
                                                const float* __restrict__ bo,
                                                float* __restrict__ out)
{
  int bid = blockIdx.x;                 // 4096 = 128 Mb x 32 Nb (Nb inner: share m-panel)
  int Mb = bid >> 5, Nb = bid & 31;
  int tid = threadIdx.x;
  int w = tid >> 6, l = tid & 63;
  int wm = w >> 1, wn = w & 1;          // 2x2 waves -> 128(m) x 128(n)
  int m0 = Mb*128 + wm*64, n0 = Nb*128 + wn*64;
  int lr = l & 15, lk = (l >> 4)*8;     // fragment lane mapping (16x16x32)
  f32x4 acc[4][4] = {};
  const short* A  = (const short*)WoT;  // rows indexed by n
  const short* Bp = (const short*)h2g;  // rows indexed by m
#pragma unroll
  for (int kk = 0; kk < 4; ++kk){
    int ko = kk*32 + lk;
    short8 av[4], bv[4];
#pragma unroll
    for (int i = 0; i < 4; ++i) av[i] = *(const short8*)(A  + (size_t)(n0 + i*16 + lr)*128 + ko);
#pragma unroll
    for (int i = 0; i < 4; ++i) bv[i] = *(const short8*)(Bp + (size_t)(m0 + i*16 + lr)*128 + ko);
#pragma unroll
    for (int fm = 0; fm < 4; ++fm)
#pragma unroll
      for (int fn = 0; fn < 4; ++fn)
        acc[fm][fn] = __builtin_amdgcn_mfma_f32_16x16x32_bf16(av[fn], bv[fm], acc[fm][fn], 0, 0, 0);
  }
  // D layout: col(lane&15) = m index, row((lane>>4)*4+reg) = n index (contiguous)
  int nb_ = (l >> 4)*4;
#pragma unroll
  for (int fn = 0; fn < 4; ++fn){
    f32x4 bia = *(const f32x4*)(bo + n0 + fn*16 + nb_);
#pragma unroll
    for (int fm = 0; fm < 4; ++fm){
      size_t row = (size_t)(m0 + fm*16 + lr)*4096;
      __builtin_nontemporal_store(acc[fm][fn] + bia, (f32x4*)(out + row + n0 + fn*16 + nb_));
    }
  }
}

extern "C" void kernel_launch(void* const* d_in, const int* in_sizes, int n_in,
                              void* d_out, int out_size, void* d_ws, size_t ws_size,
                              hipStream_t stream)
{
  const float* enc = (const float*)d_in[0];
  const float* Wx  = (const float*)d_in[1];
  const float* Wh  = (const float*)d_in[2];
  const float* bh  = (const float*)d_in[3];
  const float* W1  = (const float*)d_in[4];
  const float* b1  = (const float*)d_in[5];
  const float* g1  = (const float*)d_in[6];
  const float* be1 = (const float*)d_in[7];
  const float* W2  = (const float*)d_in[8];
  const float* b2  = (const float*)d_in[9];
  const float* g2  = (const float*)d_in[10];
  const float* be2 = (const float*)d_in[11];
  const float* Wo  = (const float*)d_in[12];
  const float* bo  = (const float*)d_in[13];
  float* out = (float*)d_out;

  const size_t xg_bytes = (size_t)16384*256*4;   // 16 MiB
  const size_t hs_bytes = (size_t)16384*64*4;    //  4 MiB
  const size_t h2_bytes = (size_t)16384*128*2;   //  4 MiB (bf16)
  const size_t wt_bytes = (size_t)4096*128*2;    //  1 MiB (bf16)
  char* ws = (char*)d_ws;
  float *xg, *hs; __hip_bfloat16 *h2g, *WoT;
  if (ws_size >= xg_bytes + hs_bytes + h2_bytes + wt_bytes){
    xg  = (float*)ws;
    hs  = (float*)(ws + xg_bytes);
    h2g = (__hip_bfloat16*)(ws + xg_bytes + hs_bytes);
    WoT = (__hip_bfloat16*)(ws + xg_bytes + hs_bytes + h2_bytes);
  } else {
    // scratch-starved fallback: xg/hs live in d_out (dead before k_out overwrites it)
    xg  = (float*)d_out;
    hs  = (float*)((char*)d_out + xg_bytes);
    h2g = (__hip_bfloat16*)ws;
    WoT = (__hip_bfloat16*)(ws + h2_bytes);
  }

  k_xg  <<<256,  256, 0, stream>>>(enc, Wx, bh, xg);
  k_wot <<<64,   256, 0, stream>>>(Wo, WoT);
  k_lstm<<<32,   256, 0, stream>>>(xg, Wh, hs);
  k_mlp <<<256,  256, 0, stream>>>(hs, W1, b1, g1, be1, W2, b2, g2, be2, h2g);
  k_out <<<4096, 256, 0, stream>>>(h2g, WoT, bo, out);
}